// Round 3
// baseline (520.806 us; speedup 1.0000x reference)
//
#include <hip/hip_runtime.h>

#define FEAT 128

typedef __attribute__((ext_vector_type(8))) short short8;   // 8 bf16 = 4 VGPRs
typedef __attribute__((ext_vector_type(4))) float f32x4;

__device__ __forceinline__ unsigned int bf16rtn(float f) {
    unsigned int u = __float_as_uint(f);
    return (u + 0x7fffu + ((u >> 16) & 1u)) >> 16;   // round-to-nearest-even
}
__device__ __forceinline__ float bf16tof(unsigned int h) {
    return __uint_as_float(h << 16);
}

// ---------------------------------------------------------------- utilities
__global__ void zero_kernel(float* __restrict__ p, int n) {
    int i = blockIdx.x * blockDim.x + threadIdx.x;
    if (i < n) p[i] = 0.0f;
}

__global__ void degcnt_kernel(const int* __restrict__ col, const float* __restrict__ w,
                              float* __restrict__ deg, int* __restrict__ cnt, int E) {
    int e = blockIdx.x * blockDim.x + threadIdx.x;
    if (e < E) {
        int c = col[e];
        atomicAdd(&deg[c], w[e]);
        atomicAdd(&cnt[c], 1);
    }
}

__global__ void dinv_kernel(float* __restrict__ deg, int N) {
    int i = blockIdx.x * blockDim.x + threadIdx.x;
    if (i < N) {
        float d = deg[i];
        deg[i] = (d > 0.0f) ? rsqrtf(d) : 0.0f;
    }
}

// ---------------------------------------------------------------- scan (exclusive, 3-phase)
__global__ __launch_bounds__(256) void scan_block_kernel(const int* __restrict__ cnt,
                                                         int* __restrict__ rowptr,
                                                         int* __restrict__ bsum, int N) {
    __shared__ int s[256];
    int t = threadIdx.x;
    int i = blockIdx.x * 256 + t;
    int own = (i < N) ? cnt[i] : 0;
    s[t] = own;
    for (int off = 1; off < 256; off <<= 1) {
        __syncthreads();
        int v = (t >= off) ? s[t - off] : 0;
        __syncthreads();
        s[t] += v;
    }
    __syncthreads();
    if (i < N) rowptr[i] = s[t] - own;
    if (t == 255) bsum[blockIdx.x] = s[255];
}

__global__ __launch_bounds__(256) void scan_bsum_kernel(int* __restrict__ bsum, int nb) {
    __shared__ int s[256];
    int t = threadIdx.x;
    int own = (t < nb) ? bsum[t] : 0;
    s[t] = own;
    for (int off = 1; off < 256; off <<= 1) {
        __syncthreads();
        int v = (t >= off) ? s[t - off] : 0;
        __syncthreads();
        s[t] += v;
    }
    __syncthreads();
    if (t < nb) bsum[t] = s[t] - own;
}

__global__ __launch_bounds__(256) void scan_add_kernel(int* __restrict__ rowptr,
                                                       const int* __restrict__ bsum,
                                                       int* __restrict__ woff, int N, int E) {
    int i = blockIdx.x * 256 + threadIdx.x;
    if (i < N) {
        int v = rowptr[i] + bsum[blockIdx.x];
        rowptr[i] = v;
        woff[i] = v;
    }
    if (i == N) rowptr[N] = E;
}

__global__ __launch_bounds__(256) void scatter_kernel(const int* __restrict__ row,
                                                      const int* __restrict__ col,
                                                      const float* __restrict__ ew,
                                                      const float* __restrict__ dinv,
                                                      int* __restrict__ woff,
                                                      int* __restrict__ srow,
                                                      float* __restrict__ snorm, int E) {
    int e = blockIdx.x * blockDim.x + threadIdx.x;
    if (e >= E) return;
    int c = col[e];
    int r = row[e];
    int p = atomicAdd(&woff[c], 1);
    srow[p] = r;
    snorm[p] = dinv[r] * ew[e] * dinv[c];
}

// ---------------------------------------------------------------- conversions
// gx (fp32 N x 128) -> hi/lo packed-bf16 planes (N x 64 uints; low half = even feat)
__global__ void convx_kernel(const float* __restrict__ x, unsigned int* __restrict__ hi,
                             unsigned int* __restrict__ lo, int total_pairs) {
    int i = blockIdx.x * blockDim.x + threadIdx.x;
    if (i >= total_pairs) return;
    float2 v = *(const float2*)(x + (size_t)i * 2);
    unsigned int h0 = bf16rtn(v.x);
    unsigned int l0 = bf16rtn(v.x - bf16tof(h0));
    unsigned int h1 = bf16rtn(v.y);
    unsigned int l1 = bf16rtn(v.y - bf16tof(h1));
    hi[i] = h0 | (h1 << 16);
    lo[i] = l0 | (l1 << 16);
}

// W (fp32 128x128 row-major [k][c]) -> transposed split planes Wt[c][k] bf16
__global__ void convw_kernel(const float* __restrict__ W, unsigned short* __restrict__ Whi,
                             unsigned short* __restrict__ Wlo) {
    int i = blockIdx.x * blockDim.x + threadIdx.x;  // 16384
    int c = i >> 7, k = i & 127;
    float w = W[(size_t)k * FEAT + c];
    unsigned int h = bf16rtn(w);
    Whi[(size_t)c * FEAT + k] = (unsigned short)h;
    Wlo[(size_t)c * FEAT + k] = (unsigned short)bf16rtn(w - bf16tof(h));
}

// ---------------------------------------------------------------- MFMA GEMM
// Out[r][:] = X[r][:] @ W, X given as hi/lo packed planes, W as Wt[c][k] hi/lo.
// 3-term split: Xhi@Whi + Xhi@Wlo + Xlo@Whi  (near-fp32 accuracy).
// Block: 256 thr = 4 waves, 64 rows x 128 cols out. A staged in LDS; B frags
// read directly from global (64KB weight set, L2-resident, shared by all blocks).
// mfma_f32_16x16x32_bf16: A[m=lane&15][k=quad*8+j]; B[k=quad*8+j][n=lane&15];
// C[row=quad*4+reg][col=lane&15]   (m89/m91/m120-verified layouts)
__global__ __launch_bounds__(256) void gemm_mfma_kernel(
    const unsigned int* __restrict__ Xhi, const unsigned int* __restrict__ Xlo,
    const unsigned short* __restrict__ Wthi, const unsigned short* __restrict__ Wtlo,
    unsigned int* __restrict__ OutB,   // N x 64 packed bf16 (gather plane)
    int N)
{
    __shared__ unsigned short xhi[64][136];
    __shared__ unsigned short xlo[64][136];

    const int tid = threadIdx.x;
    const int r0 = blockIdx.x * 64;

    // stage X tile: 64 rows x 64 uints per plane, uint4 coalesced
#pragma unroll
    for (int it = 0; it < 4; ++it) {
        int idx = it * 256 + tid;        // 0..1023
        int r = idx >> 4;
        int c4 = (idx & 15) * 4;         // uint offset
        int gr = r0 + r;
        uint4 vh = make_uint4(0, 0, 0, 0), vl = make_uint4(0, 0, 0, 0);
        if (gr < N) {
            vh = *(const uint4*)(Xhi + (size_t)gr * 64 + c4);
            vl = *(const uint4*)(Xlo + (size_t)gr * 64 + c4);
        }
        *(uint4*)&xhi[r][c4 * 2] = vh;
        *(uint4*)&xlo[r][c4 * 2] = vl;
    }
    __syncthreads();

    const int lane = tid & 63;
    const int wv = tid >> 6;
    const int m = lane & 15;
    const int quad = lane >> 4;
    const int arow = wv * 16 + m;

    f32x4 acc[8];
#pragma unroll
    for (int ct = 0; ct < 8; ++ct) acc[ct] = (f32x4){0.f, 0.f, 0.f, 0.f};

#pragma unroll
    for (int kt = 0; kt < 4; ++kt) {
        const int k0 = kt * 32 + quad * 8;
        short8 ah = *(const short8*)&xhi[arow][k0];
        short8 al = *(const short8*)&xlo[arow][k0];
#pragma unroll
        for (int ct = 0; ct < 8; ++ct) {
            int bcol = ct * 16 + m;
            short8 bh = *(const short8*)(Wthi + (size_t)bcol * FEAT + k0);
            short8 bl = *(const short8*)(Wtlo + (size_t)bcol * FEAT + k0);
            acc[ct] = __builtin_amdgcn_mfma_f32_16x16x32_bf16(ah, bh, acc[ct], 0, 0, 0);
            acc[ct] = __builtin_amdgcn_mfma_f32_16x16x32_bf16(ah, bl, acc[ct], 0, 0, 0);
            acc[ct] = __builtin_amdgcn_mfma_f32_16x16x32_bf16(al, bh, acc[ct], 0, 0, 0);
        }
    }

    // store C as bf16 (scalar ushort stores; lanes 0-15 contiguous 32B segments)
    unsigned short* outu = (unsigned short*)OutB;
#pragma unroll
    for (int ct = 0; ct < 8; ++ct) {
        int col = ct * 16 + m;
#pragma unroll
        for (int reg = 0; reg < 4; ++reg) {
            int gr = r0 + wv * 16 + quad * 4 + reg;
            if (gr < N) {
                outu[(size_t)gr * FEAT + col] = (unsigned short)bf16rtn(acc[ct][reg]);
            }
        }
    }
}

// ---------------------------------------------------------------- CSR aggregation
// One wave per destination node (4 nodes per block); lane owns features 2l, 2l+1.
// Gathers packed bf16 pairs (1 uint/lane/edge), accumulates fp32.
// FINAL=0: relu, split into hi/lo packed planes (next GEMM input).
// FINAL=1: store fp32 to d_out + atomic readout.
template <int FINAL>
__global__ __launch_bounds__(256) void agg_ms_kernel(
    const int* __restrict__ rowptr, const int* __restrict__ srow,
    const float* __restrict__ snorm,
    const unsigned int* __restrict__ hb,   // N x 64 packed bf16
    const float* __restrict__ bias,
    unsigned int* __restrict__ outHi, unsigned int* __restrict__ outLo,
    float* __restrict__ out_f32,
    const int* __restrict__ batch, float* __restrict__ ro,
    int N)
{
    const int node = blockIdx.x * 4 + (threadIdx.x >> 6);
    if (node >= N) return;
    const int lane = threadIdx.x & 63;
    const int s = rowptr[node];
    const int e = rowptr[node + 1];

    float2 bv = *(const float2*)(bias + lane * 2);
    float a0 = bv.x, a1 = bv.y;

    int i = s;
    for (; i + 4 <= e; i += 4) {
        int r0 = srow[i], r1 = srow[i + 1], r2 = srow[i + 2], r3 = srow[i + 3];
        float w0 = snorm[i], w1 = snorm[i + 1], w2 = snorm[i + 2], w3 = snorm[i + 3];
        unsigned int v0 = hb[(size_t)r0 * 64 + lane];
        unsigned int v1 = hb[(size_t)r1 * 64 + lane];
        unsigned int v2 = hb[(size_t)r2 * 64 + lane];
        unsigned int v3 = hb[(size_t)r3 * 64 + lane];
        a0 = fmaf(w0, __uint_as_float(v0 << 16), a0);
        a1 = fmaf(w0, __uint_as_float(v0 & 0xffff0000u), a1);
        a0 = fmaf(w1, __uint_as_float(v1 << 16), a0);
        a1 = fmaf(w1, __uint_as_float(v1 & 0xffff0000u), a1);
        a0 = fmaf(w2, __uint_as_float(v2 << 16), a0);
        a1 = fmaf(w2, __uint_as_float(v2 & 0xffff0000u), a1);
        a0 = fmaf(w3, __uint_as_float(v3 << 16), a0);
        a1 = fmaf(w3, __uint_as_float(v3 & 0xffff0000u), a1);
    }
    for (; i < e; ++i) {
        float w = snorm[i];
        unsigned int v = hb[(size_t)srow[i] * 64 + lane];
        a0 = fmaf(w, __uint_as_float(v << 16), a0);
        a1 = fmaf(w, __uint_as_float(v & 0xffff0000u), a1);
    }

    if (!FINAL) {
        a0 = fmaxf(a0, 0.0f);
        a1 = fmaxf(a1, 0.0f);
        unsigned int h0 = bf16rtn(a0);
        unsigned int l0 = bf16rtn(a0 - bf16tof(h0));
        unsigned int h1 = bf16rtn(a1);
        unsigned int l1 = bf16rtn(a1 - bf16tof(h1));
        outHi[(size_t)node * 64 + lane] = h0 | (h1 << 16);
        outLo[(size_t)node * 64 + lane] = l0 | (l1 << 16);
    } else {
        *(float2*)(out_f32 + (size_t)node * FEAT + lane * 2) = make_float2(a0, a1);
        float* rp = ro + (size_t)batch[node] * FEAT + lane * 2;
        atomicAdd(rp, a0);
        atomicAdd(rp + 1, a1);
    }
}

// ---------------------------------------------------------------- launch
static inline size_t align256(size_t x) { return (x + 255) & ~(size_t)255; }

extern "C" void kernel_launch(void* const* d_in, const int* in_sizes, int n_in,
                              void* d_out, int out_size, void* d_ws, size_t ws_size,
                              hipStream_t stream) {
    const float* gx    = (const float*)d_in[0];
    const int*   ei    = (const int*)d_in[1];
    const int*   batch = (const int*)d_in[2];
    const float* ew    = (const float*)d_in[3];
    const float* W1 = (const float*)d_in[4];
    const float* b1 = (const float*)d_in[5];
    const float* W2 = (const float*)d_in[6];
    const float* b2 = (const float*)d_in[7];
    const float* W3 = (const float*)d_in[8];
    const float* b3 = (const float*)d_in[9];

    const int N = in_sizes[0] / FEAT;            // 50000
    const int E = in_sizes[3];                   // 800000
    const int G = (out_size - N * FEAT) / FEAT;  // 256

    const int* row = ei;
    const int* col = ei + E;

    // ---- workspace layout
    char* ws = (char*)d_ws;
    float* deg    = (float*)ws;  ws += align256((size_t)N * 4);
    int*   cnt    = (int*)ws;    ws += align256((size_t)N * 4);
    int*   rowptr = (int*)ws;    ws += align256((size_t)(N + 1) * 4);
    int*   woff   = (int*)ws;    ws += align256((size_t)N * 4);
    int*   bsum   = (int*)ws;    ws += align256(256 * 4);
    int*   srow   = (int*)ws;    ws += align256((size_t)E * 4);
    float* snorm  = (float*)ws;  ws += align256((size_t)E * 4);
    unsigned int* Xhi  = (unsigned int*)ws;  ws += align256((size_t)N * 64 * 4);
    unsigned int* Xlo  = (unsigned int*)ws;  ws += align256((size_t)N * 64 * 4);
    unsigned int* bufA = (unsigned int*)ws;  ws += align256((size_t)N * 64 * 4);
    unsigned short* Wt1h = (unsigned short*)ws; ws += align256(16384 * 2);
    unsigned short* Wt1l = (unsigned short*)ws; ws += align256(16384 * 2);
    unsigned short* Wt2h = (unsigned short*)ws; ws += align256(16384 * 2);
    unsigned short* Wt2l = (unsigned short*)ws; ws += align256(16384 * 2);
    unsigned short* Wt3h = (unsigned short*)ws; ws += align256(16384 * 2);
    unsigned short* Wt3l = (unsigned short*)ws; ws += align256(16384 * 2);

    float* h_out = (float*)d_out;
    float* ro    = h_out + (size_t)N * FEAT;

    const int NB = (N + 255) / 256;
    const int EB = (E + 255) / 256;
    const int nb = NB;

    // ---- degree + counts + dinv
    zero_kernel<<<(2 * N + 255) / 256, 256, 0, stream>>>(deg, 2 * N);  // deg + cnt contiguous? no:
    // deg and cnt are in separate aligned segments; zero each explicitly
    zero_kernel<<<NB, 256, 0, stream>>>((float*)cnt, N);
    degcnt_kernel<<<EB, 256, 0, stream>>>(col, ew, deg, cnt, E);
    dinv_kernel<<<NB, 256, 0, stream>>>(deg, N);

    // ---- CSR build
    scan_block_kernel<<<nb, 256, 0, stream>>>(cnt, rowptr, bsum, N);
    scan_bsum_kernel<<<1, 256, 0, stream>>>(bsum, nb);
    scan_add_kernel<<<nb + 1, 256, 0, stream>>>(rowptr, bsum, woff, N, E);
    scatter_kernel<<<EB, 256, 0, stream>>>(row, col, ew, deg, woff, srow, snorm, E);

    // ---- conversions
    convx_kernel<<<(N * 64 + 255) / 256, 256, 0, stream>>>(gx, Xhi, Xlo, N * 64);
    convw_kernel<<<64, 256, 0, stream>>>(W1, Wt1h, Wt1l);
    convw_kernel<<<64, 256, 0, stream>>>(W2, Wt2h, Wt2l);
    convw_kernel<<<64, 256, 0, stream>>>(W3, Wt3h, Wt3l);

    const int gblocks = (N + 63) / 64;
    const int ablocks = (N + 3) / 4;

    // ---- layer 1
    gemm_mfma_kernel<<<gblocks, 256, 0, stream>>>(Xhi, Xlo, Wt1h, Wt1l, bufA, N);
    agg_ms_kernel<0><<<ablocks, 256, 0, stream>>>(rowptr, srow, snorm, bufA, b1,
                                                  Xhi, Xlo, nullptr, nullptr, nullptr, N);
    // ---- layer 2
    gemm_mfma_kernel<<<gblocks, 256, 0, stream>>>(Xhi, Xlo, Wt2h, Wt2l, bufA, N);
    agg_ms_kernel<0><<<ablocks, 256, 0, stream>>>(rowptr, srow, snorm, bufA, b2,
                                                  Xhi, Xlo, nullptr, nullptr, nullptr, N);
    // ---- layer 3 + fused readout
    gemm_mfma_kernel<<<gblocks, 256, 0, stream>>>(Xhi, Xlo, Wt3h, Wt3l, bufA, N);
    zero_kernel<<<(G * FEAT + 255) / 256, 256, 0, stream>>>(ro, G * FEAT);
    agg_ms_kernel<1><<<ablocks, 256, 0, stream>>>(rowptr, srow, snorm, bufA, b3,
                                                  nullptr, nullptr, h_out, batch, ro, N);
}

// Round 4
// 423.291 us; speedup vs baseline: 1.2304x; 1.2304x over previous
//
#include <hip/hip_runtime.h>

#define FEAT 128

typedef __attribute__((ext_vector_type(8))) short short8;   // 8 bf16 = 4 VGPRs
typedef __attribute__((ext_vector_type(4))) float f32x4;

__device__ __forceinline__ unsigned int bf16rtn(float f) {
    unsigned int u = __float_as_uint(f);
    return (u + 0x7fffu + ((u >> 16) & 1u)) >> 16;   // round-to-nearest-even
}
__device__ __forceinline__ float bf16tof(unsigned int h) { return __uint_as_float(h << 16); }
__device__ __forceinline__ float bf16lo(unsigned int v) { return __uint_as_float(v << 16); }
__device__ __forceinline__ float bf16hi(unsigned int v) { return __uint_as_float(v & 0xffff0000u); }

// ---------------------------------------------------------------- utilities
__global__ void zero_kernel(float* __restrict__ p, int n) {
    int i = blockIdx.x * blockDim.x + threadIdx.x;
    if (i < n) p[i] = 0.0f;
}

__global__ void degcnt_kernel(const int* __restrict__ col, const float* __restrict__ w,
                              float* __restrict__ deg, int* __restrict__ cnt, int E) {
    int e = blockIdx.x * blockDim.x + threadIdx.x;
    if (e < E) {
        int c = col[e];
        atomicAdd(&deg[c], w[e]);
        atomicAdd(&cnt[c], 1);
    }
}

__global__ void dinv_kernel(float* __restrict__ deg, int N) {
    int i = blockIdx.x * blockDim.x + threadIdx.x;
    if (i < N) {
        float d = deg[i];
        deg[i] = (d > 0.0f) ? rsqrtf(d) : 0.0f;
    }
}

// ---------------------------------------------------------------- scan (exclusive, 3-phase)
__global__ __launch_bounds__(256) void scan_block_kernel(const int* __restrict__ cnt,
                                                         int* __restrict__ rowptr,
                                                         int* __restrict__ bsum, int N) {
    __shared__ int s[256];
    int t = threadIdx.x;
    int i = blockIdx.x * 256 + t;
    int own = (i < N) ? cnt[i] : 0;
    s[t] = own;
    for (int off = 1; off < 256; off <<= 1) {
        __syncthreads();
        int v = (t >= off) ? s[t - off] : 0;
        __syncthreads();
        s[t] += v;
    }
    __syncthreads();
    if (i < N) rowptr[i] = s[t] - own;
    if (t == 255) bsum[blockIdx.x] = s[255];
}

__global__ __launch_bounds__(256) void scan_bsum_kernel(int* __restrict__ bsum, int nb) {
    __shared__ int s[256];
    int t = threadIdx.x;
    int own = (t < nb) ? bsum[t] : 0;
    s[t] = own;
    for (int off = 1; off < 256; off <<= 1) {
        __syncthreads();
        int v = (t >= off) ? s[t - off] : 0;
        __syncthreads();
        s[t] += v;
    }
    __syncthreads();
    if (t < nb) bsum[t] = s[t] - own;
}

__global__ __launch_bounds__(256) void scan_add_kernel(int* __restrict__ rowptr,
                                                       const int* __restrict__ bsum,
                                                       int* __restrict__ woff, int N, int E) {
    int i = blockIdx.x * 256 + threadIdx.x;
    if (i < N) {
        int v = rowptr[i] + bsum[blockIdx.x];
        rowptr[i] = v;
        woff[i] = v;
    }
    if (i == N) rowptr[N] = E;
}

// scatter edges into destination-grouped order; (row, norm) packed as one uint2
__global__ __launch_bounds__(256) void scatter_kernel(const int* __restrict__ row,
                                                      const int* __restrict__ col,
                                                      const float* __restrict__ ew,
                                                      const float* __restrict__ dinv,
                                                      int* __restrict__ woff,
                                                      uint2* __restrict__ sedge, int E) {
    int e = blockIdx.x * blockDim.x + threadIdx.x;
    if (e >= E) return;
    int c = col[e];
    int r = row[e];
    float nw = dinv[r] * ew[e] * dinv[c];
    int p = atomicAdd(&woff[c], 1);
    sedge[p] = make_uint2((unsigned)r, __float_as_uint(nw));
}

// W (fp32 128x128 [k][c]) -> transposed split planes Wt[c][k] bf16 hi/lo
__global__ void convw_kernel(const float* __restrict__ W, unsigned short* __restrict__ Whi,
                             unsigned short* __restrict__ Wlo) {
    int i = blockIdx.x * blockDim.x + threadIdx.x;  // 16384
    int c = i >> 7, k = i & 127;
    float w = W[(size_t)k * FEAT + c];
    unsigned int h = bf16rtn(w);
    Whi[(size_t)c * FEAT + k] = (unsigned short)h;
    Wlo[(size_t)c * FEAT + k] = (unsigned short)bf16rtn(w - bf16tof(h));
}

// ---------------------------------------------------------------- MFMA GEMM
// Tile: 64 rows x 64 cols (blockIdx.y selects col half). X fp32 -> split hi/lo
// bf16 in LDS during staging; W hi/lo planes staged in LDS (Wt[c][k] layout).
// 3-term split GEMM: Xhi@Whi + Xhi@Wlo + Xlo@Whi (near-fp32).
// LDS arrays are XOR-swizzled (k8 ^ ((row&7)<<3)) instead of padded: b128
// fragment reads land on 8 distinct banks x 2-way (free), total LDS = 64 KB
// exactly -> 2 blocks/CU.
// mfma_f32_16x16x32_bf16: A[m=lane&15][k=quad*8+j]; B[k][n=lane&15];
// C[row=quad*4+reg][col=lane&15]  (verified via R3 pass)
__global__ __launch_bounds__(256) void gemm_mfma_kernel(
    const float* __restrict__ X,
    const unsigned short* __restrict__ Wthi, const unsigned short* __restrict__ Wtlo,
    unsigned int* __restrict__ hb,   // N x 64 packed bf16 out
    int N)
{
    __shared__ unsigned short xh[64 * 128];
    __shared__ unsigned short xl[64 * 128];
    __shared__ unsigned short wh[64 * 128];
    __shared__ unsigned short wl[64 * 128];

    const int tid = threadIdx.x;
    const int r0 = blockIdx.x * 64;
    const int cb = blockIdx.y;       // col half: 0 or 1

    // ---- stage W tile: 64 cols x 128 k, both planes, 16B vectors
#pragma unroll
    for (int it = 0; it < 4; ++it) {
        int idx = it * 256 + tid;    // 0..1023
        int c = idx >> 4;            // 0..63
        int k8 = (idx & 15) * 8;     // 0..120
        int sw = k8 ^ ((c & 7) << 3);
        size_t src = (size_t)(cb * 64 + c) * FEAT + k8;
        *(short8*)&wh[c * 128 + sw] = *(const short8*)(Wthi + src);
        *(short8*)&wl[c * 128 + sw] = *(const short8*)(Wtlo + src);
    }
    // ---- stage X tile: 64 rows x 128 k fp32, split to hi/lo bf16
#pragma unroll
    for (int it = 0; it < 8; ++it) {
        int idx = it * 256 + tid;    // 0..2047
        int r = idx >> 5;            // 0..63
        int kc = (idx & 31) * 4;     // 0..124
        int gr = r0 + r;
        float4 v = make_float4(0.f, 0.f, 0.f, 0.f);
        if (gr < N) v = *(const float4*)(X + (size_t)gr * FEAT + kc);
        unsigned int h0 = bf16rtn(v.x), h1 = bf16rtn(v.y);
        unsigned int h2 = bf16rtn(v.z), h3 = bf16rtn(v.w);
        ushort4 hv = make_ushort4((unsigned short)h0, (unsigned short)h1,
                                  (unsigned short)h2, (unsigned short)h3);
        ushort4 lv = make_ushort4((unsigned short)bf16rtn(v.x - bf16tof(h0)),
                                  (unsigned short)bf16rtn(v.y - bf16tof(h1)),
                                  (unsigned short)bf16rtn(v.z - bf16tof(h2)),
                                  (unsigned short)bf16rtn(v.w - bf16tof(h3)));
        int sw = kc ^ ((r & 7) << 3);   // kc%8 in {0,4}: low bits preserved
        *(ushort4*)&xh[r * 128 + sw] = hv;
        *(ushort4*)&xl[r * 128 + sw] = lv;
    }
    __syncthreads();

    const int lane = tid & 63;
    const int wv = tid >> 6;
    const int m = lane & 15;
    const int quad = lane >> 4;
    const int arow = wv * 16 + m;

    f32x4 acc[4];
#pragma unroll
    for (int ct = 0; ct < 4; ++ct) acc[ct] = (f32x4){0.f, 0.f, 0.f, 0.f};

#pragma unroll
    for (int kt = 0; kt < 4; ++kt) {
        const int k0 = kt * 32 + quad * 8;
        const int aw = k0 ^ ((arow & 7) << 3);
        short8 ah = *(const short8*)&xh[arow * 128 + aw];
        short8 al = *(const short8*)&xl[arow * 128 + aw];
#pragma unroll
        for (int ct = 0; ct < 4; ++ct) {
            int bc = ct * 16 + m;
            int bw = k0 ^ ((bc & 7) << 3);
            short8 bh = *(const short8*)&wh[bc * 128 + bw];
            short8 bl = *(const short8*)&wl[bc * 128 + bw];
            acc[ct] = __builtin_amdgcn_mfma_f32_16x16x32_bf16(ah, bh, acc[ct], 0, 0, 0);
            acc[ct] = __builtin_amdgcn_mfma_f32_16x16x32_bf16(ah, bl, acc[ct], 0, 0, 0);
            acc[ct] = __builtin_amdgcn_mfma_f32_16x16x32_bf16(al, bh, acc[ct], 0, 0, 0);
        }
    }

    // ---- epilogue: LDS transpose (reuse xh) -> coalesced packed-uint4 stores
    __syncthreads();
    unsigned short* cl = xh;   // 64 rows x stride 72 (144B, 16B-aligned rows)
#pragma unroll
    for (int ct = 0; ct < 4; ++ct)
#pragma unroll
        for (int reg = 0; reg < 4; ++reg) {
            int rrow = wv * 16 + quad * 4 + reg;
            cl[rrow * 72 + ct * 16 + m] = (unsigned short)bf16rtn(acc[ct][reg]);
        }
    __syncthreads();
#pragma unroll
    for (int it = 0; it < 2; ++it) {
        int idx = it * 256 + tid;    // 0..511
        int r = idx >> 3;            // 0..63
        int c4 = (idx & 7) * 4;      // uint offset 0..28
        int gr = r0 + r;
        if (gr < N) {
            uint4 pv = *(const uint4*)&cl[r * 72 + c4 * 2];
            *(uint4*)(hb + (size_t)gr * 64 + cb * 32 + c4) = pv;
        }
    }
}

// ---------------------------------------------------------------- CSR aggregation
// One wave per destination node (4/block). Wave loads up to 64 (row,norm)
// pairs in ONE uint2 vector load, broadcasts via __shfl (LDS pipe), then
// issues one 256B gather per edge with full-degree MLP. fp32 accumulate.
// FINAL=0: relu + fp32 store (next GEMM input). FINAL=1: fp32 store to
// d_out + atomic readout accumulate.
template <int FINAL>
__global__ __launch_bounds__(256) void agg_gather_kernel(
    const int* __restrict__ rowptr, const uint2* __restrict__ sedge,
    const unsigned int* __restrict__ hb, const float* __restrict__ bias,
    float* __restrict__ outX, const int* __restrict__ batch,
    float* __restrict__ ro, int N)
{
    const int node = blockIdx.x * 4 + (threadIdx.x >> 6);
    if (node >= N) return;
    const int lane = threadIdx.x & 63;
    const int s = rowptr[node];
    const int e = rowptr[node + 1];

    float2 bv = *(const float2*)(bias + lane * 2);
    float a0 = bv.x, a1 = bv.y;

    for (int base = s; base < e; base += 64) {
        int idx = base + lane;
        uint2 p = make_uint2(0u, 0u);          // invalid lanes: r=0, w=0.0f
        if (idx < e) p = sedge[idx];
        int rL = (int)p.x;
        int wL = (int)p.y;
        int cnt4 = (min(64, e - base) + 3) & ~3;
        for (int j = 0; j < cnt4; j += 4) {
            int r0 = __shfl(rL, j);
            int r1 = __shfl(rL, j + 1);
            int r2 = __shfl(rL, j + 2);
            int r3 = __shfl(rL, j + 3);
            float w0 = __uint_as_float((unsigned)__shfl(wL, j));
            float w1 = __uint_as_float((unsigned)__shfl(wL, j + 1));
            float w2 = __uint_as_float((unsigned)__shfl(wL, j + 2));
            float w3 = __uint_as_float((unsigned)__shfl(wL, j + 3));
            unsigned v0 = hb[(size_t)r0 * 64 + lane];
            unsigned v1 = hb[(size_t)r1 * 64 + lane];
            unsigned v2 = hb[(size_t)r2 * 64 + lane];
            unsigned v3 = hb[(size_t)r3 * 64 + lane];
            a0 = fmaf(w0, bf16lo(v0), a0);  a1 = fmaf(w0, bf16hi(v0), a1);
            a0 = fmaf(w1, bf16lo(v1), a0);  a1 = fmaf(w1, bf16hi(v1), a1);
            a0 = fmaf(w2, bf16lo(v2), a0);  a1 = fmaf(w2, bf16hi(v2), a1);
            a0 = fmaf(w3, bf16lo(v3), a0);  a1 = fmaf(w3, bf16hi(v3), a1);
        }
    }

    if (!FINAL) {
        a0 = fmaxf(a0, 0.0f);
        a1 = fmaxf(a1, 0.0f);
        *(float2*)(outX + (size_t)node * FEAT + lane * 2) = make_float2(a0, a1);
    } else {
        *(float2*)(outX + (size_t)node * FEAT + lane * 2) = make_float2(a0, a1);
        float* rp = ro + (size_t)batch[node] * FEAT + lane * 2;
        atomicAdd(rp, a0);
        atomicAdd(rp + 1, a1);
    }
}

// ---------------------------------------------------------------- launch
static inline size_t align256(size_t x) { return (x + 255) & ~(size_t)255; }

extern "C" void kernel_launch(void* const* d_in, const int* in_sizes, int n_in,
                              void* d_out, int out_size, void* d_ws, size_t ws_size,
                              hipStream_t stream) {
    const float* gx    = (const float*)d_in[0];
    const int*   ei    = (const int*)d_in[1];
    const int*   batch = (const int*)d_in[2];
    const float* ew    = (const float*)d_in[3];
    const float* W1 = (const float*)d_in[4];
    const float* b1 = (const float*)d_in[5];
    const float* W2 = (const float*)d_in[6];
    const float* b2 = (const float*)d_in[7];
    const float* W3 = (const float*)d_in[8];
    const float* b3 = (const float*)d_in[9];

    const int N = in_sizes[0] / FEAT;            // 50000
    const int E = in_sizes[3];                   // 800000
    const int G = (out_size - N * FEAT) / FEAT;  // 256

    const int* row = ei;
    const int* col = ei + E;

    // ---- workspace layout
    char* ws = (char*)d_ws;
    float* deg    = (float*)ws;                                  // deg -> dinv in place
    int*   cnt    = (int*)(deg + N);  ws += align256((size_t)2 * N * 4);
    int*   rowptr = (int*)ws;         ws += align256((size_t)(N + 1) * 4);
    int*   woff   = (int*)ws;         ws += align256((size_t)N * 4);
    int*   bsum   = (int*)ws;         ws += align256(256 * 4);
    uint2* sedge  = (uint2*)ws;       ws += align256((size_t)E * 8);
    unsigned int* hb = (unsigned int*)ws;  ws += align256((size_t)N * 64 * 4);
    float* bufX   = (float*)ws;       ws += align256((size_t)N * FEAT * 4);
    unsigned short* Wt1h = (unsigned short*)ws; ws += align256(16384 * 2);
    unsigned short* Wt1l = (unsigned short*)ws; ws += align256(16384 * 2);
    unsigned short* Wt2h = (unsigned short*)ws; ws += align256(16384 * 2);
    unsigned short* Wt2l = (unsigned short*)ws; ws += align256(16384 * 2);
    unsigned short* Wt3h = (unsigned short*)ws; ws += align256(16384 * 2);
    unsigned short* Wt3l = (unsigned short*)ws; ws += align256(16384 * 2);

    float* h_out = (float*)d_out;
    float* ro    = h_out + (size_t)N * FEAT;

    const int NB = (N + 255) / 256;
    const int EB = (E + 255) / 256;
    const int nb = NB;

    // ---- degree + counts + dinv (deg,cnt contiguous -> one zero pass)
    zero_kernel<<<(2 * N + 255) / 256, 256, 0, stream>>>(deg, 2 * N);
    degcnt_kernel<<<EB, 256, 0, stream>>>(col, ew, deg, cnt, E);
    dinv_kernel<<<NB, 256, 0, stream>>>(deg, N);

    // ---- CSR build
    scan_block_kernel<<<nb, 256, 0, stream>>>(cnt, rowptr, bsum, N);
    scan_bsum_kernel<<<1, 256, 0, stream>>>(bsum, nb);
    scan_add_kernel<<<nb + 1, 256, 0, stream>>>(rowptr, bsum, woff, N, E);
    scatter_kernel<<<EB, 256, 0, stream>>>(row, col, ew, deg, woff, sedge, E);

    // ---- weight conversion (tiny)
    convw_kernel<<<64, 256, 0, stream>>>(W1, Wt1h, Wt1l);
    convw_kernel<<<64, 256, 0, stream>>>(W2, Wt2h, Wt2l);
    convw_kernel<<<64, 256, 0, stream>>>(W3, Wt3h, Wt3l);

    dim3 ggrid((N + 63) / 64, 2);
    const int ablocks = (N + 3) / 4;

    // ---- layer 1 (GEMM reads gx fp32 directly; no convx)
    gemm_mfma_kernel<<<ggrid, 256, 0, stream>>>(gx, Wt1h, Wt1l, hb, N);
    agg_gather_kernel<0><<<ablocks, 256, 0, stream>>>(rowptr, sedge, hb, b1, bufX,
                                                      nullptr, nullptr, N);
    // ---- layer 2
    gemm_mfma_kernel<<<ggrid, 256, 0, stream>>>(bufX, Wt2h, Wt2l, hb, N);
    agg_gather_kernel<0><<<ablocks, 256, 0, stream>>>(rowptr, sedge, hb, b2, bufX,
                                                      nullptr, nullptr, N);
    // ---- layer 3 + fused readout
    gemm_mfma_kernel<<<ggrid, 256, 0, stream>>>(bufX, Wt3h, Wt3l, hb, N);
    zero_kernel<<<(G * FEAT + 255) / 256, 256, 0, stream>>>(ro, G * FEAT);
    agg_gather_kernel<1><<<ablocks, 256, 0, stream>>>(rowptr, sedge, hb, b3, h_out,
                                                      batch, ro, N);
}